// Round 1
// baseline (651.673 us; speedup 1.0000x reference)
//
#include <hip/hip_runtime.h>
#include <hip/hip_bf16.h>
#include <math.h>

// Problem constants (from reference): BS*SEQ tokens, top-1 expert per token.
#define TOK   4096
#define DIM   1024
#define DMLP  4096
#define NE    8
#define BM    128
#define BN    128
#define BK    32
#define PADMAX (TOK + NE * BM)   // 5120 padded slots
#define NTILES (PADMAX / BM)     // 40 row-tiles (some inactive)

typedef __attribute__((ext_vector_type(8))) short  short8;
typedef __attribute__((ext_vector_type(4))) float  float4v;

static __device__ __forceinline__ unsigned short f2bf(float f) {
  // round-to-nearest-even f32 -> bf16
  unsigned u = __float_as_uint(f);
  u += 0x7fffu + ((u >> 16) & 1u);
  return (unsigned short)(u >> 16);
}

// ---------------------------------------------------------------------------
// Kernel 1: group tokens by expert. Single block.
// perm[slot] = token index (or -1 pad), segments padded to BM, tile_e[t] = expert.
// ---------------------------------------------------------------------------
__global__ void group_kernel(const int* __restrict__ eidx,
                             int* __restrict__ perm,
                             int* __restrict__ tile_e) {
  __shared__ int cnt[NE], off[NE], len[NE], cur[NE];
  const int tid = threadIdx.x;
  if (tid < NE) cnt[tid] = 0;
  __syncthreads();
  for (int i = tid; i < TOK; i += 256) atomicAdd(&cnt[eidx[i]], 1);
  __syncthreads();
  if (tid == 0) {
    int o = 0;
    for (int e = 0; e < NE; e++) {
      off[e] = o;
      len[e] = ((cnt[e] + BM - 1) / BM) * BM;
      cur[e] = o;
      o += len[e];
    }
  }
  __syncthreads();
  for (int s = tid; s < PADMAX; s += 256) perm[s] = -1;
  __syncthreads();
  for (int i = tid; i < TOK; i += 256) {
    const int e = eidx[i];
    const int p = atomicAdd(&cur[e], 1);
    perm[p] = i;
  }
  __syncthreads();
  for (int t = tid; t < NTILES; t += 256) {
    const int row = t * BM;
    int te = -1;
    for (int e = 0; e < NE; e++)
      if (row >= off[e] && row < off[e] + len[e]) te = e;
    tile_e[t] = te;
  }
}

// ---------------------------------------------------------------------------
// Kernel 2: h = gelu(x[perm] @ W1[e] + b1[e])  -> bf16 workspace
// 128x128 tile, BK=32, 4 waves x (4x4) mfma_f32_16x16x32_bf16
// ---------------------------------------------------------------------------
__global__ __launch_bounds__(256, 2)
void gemm1_kernel(const float* __restrict__ x, const float* __restrict__ W1,
                  const float* __restrict__ b1, const int* __restrict__ perm,
                  const int* __restrict__ tile_e, unsigned short* __restrict__ h) {
  const int te = tile_e[blockIdx.x];
  if (te < 0) return;
  const float* W = W1 + (size_t)te * DIM * DMLP;
  const int n0 = blockIdx.y * BN;
  const int tid = threadIdx.x;

  __shared__ unsigned short As[BM][BK + 8];   // pad to 40 shorts (80B) per row
  __shared__ unsigned short Bs[BN][BK + 8];

  // A staging: thread -> (row, 16-wide k chunk)
  const int arow = tid >> 1;
  const int acol = (tid & 1) * 16;
  const int tok  = perm[blockIdx.x * BM + arow];
  const float* xrow = x + (size_t)(tok < 0 ? 0 : tok) * DIM + acol;

  // B staging: thread -> (column n, 16 consecutive k)
  const int bn  = tid & 127;
  const int bk0 = (tid >> 7) * 16;
  const float* wcol = W + n0 + bn;

  const int wid = tid >> 6, lane = tid & 63;
  const int wm = (wid >> 1) * 64, wn = (wid & 1) * 64;
  const int l15 = lane & 15, quad = lane >> 4;

  float4v acc[4][4];
#pragma unroll
  for (int i = 0; i < 4; i++)
#pragma unroll
    for (int j = 0; j < 4; j++) acc[i][j] = (float4v){0.f, 0.f, 0.f, 0.f};

  for (int k0 = 0; k0 < DIM; k0 += BK) {
    // ---- stage A (gathered x rows, f32 -> bf16) ----
    float av[16];
#pragma unroll
    for (int v = 0; v < 4; v++) {
      float4v t4 = *(const float4v*)(xrow + k0 + v * 4);
#pragma unroll
      for (int q = 0; q < 4; q++) av[v * 4 + q] = t4[q];
    }
    if (tok < 0) {
#pragma unroll
      for (int q = 0; q < 16; q++) av[q] = 0.f;
    }
    short8 ap0, ap1;
#pragma unroll
    for (int q = 0; q < 8; q++) { ap0[q] = (short)f2bf(av[q]); ap1[q] = (short)f2bf(av[q + 8]); }
    *(short8*)&As[arow][acol]     = ap0;
    *(short8*)&As[arow][acol + 8] = ap1;

    // ---- stage B (W1 tile, transpose to [n][k], f32 -> bf16) ----
    float bv[16];
#pragma unroll
    for (int j = 0; j < 16; j++) bv[j] = wcol[(size_t)(k0 + bk0 + j) * DMLP];
    short8 bp0, bp1;
#pragma unroll
    for (int q = 0; q < 8; q++) { bp0[q] = (short)f2bf(bv[q]); bp1[q] = (short)f2bf(bv[q + 8]); }
    *(short8*)&Bs[bn][bk0]     = bp0;
    *(short8*)&Bs[bn][bk0 + 8] = bp1;

    __syncthreads();

    short8 a[4], b[4];
#pragma unroll
    for (int i = 0; i < 4; i++) a[i] = *(short8*)&As[wm + i * 16 + l15][quad * 8];
#pragma unroll
    for (int j = 0; j < 4; j++) b[j] = *(short8*)&Bs[wn + j * 16 + l15][quad * 8];
#pragma unroll
    for (int i = 0; i < 4; i++)
#pragma unroll
      for (int j = 0; j < 4; j++)
        acc[i][j] = __builtin_amdgcn_mfma_f32_16x16x32_bf16(a[i], b[j], acc[i][j], 0, 0, 0);

    __syncthreads();
  }

  // ---- epilogue: bias + exact gelu -> bf16 h ----
#pragma unroll
  for (int i = 0; i < 4; i++) {
#pragma unroll
    for (int j = 0; j < 4; j++) {
      const int col = n0 + wn + j * 16 + l15;
      const float bias = b1[te * DMLP + col];
#pragma unroll
      for (int r = 0; r < 4; r++) {
        const int row = wm + i * 16 + quad * 4 + r;
        float v = acc[i][j][r] + bias;
        v = 0.5f * v * (1.0f + erff(v * 0.7071067811865475f));
        h[(size_t)(blockIdx.x * BM + row) * DMLP + col] = f2bf(v);
      }
    }
  }
}

// ---------------------------------------------------------------------------
// Kernel 3: out[tok] = h @ W2[e] + b2[e], scatter per token
// ---------------------------------------------------------------------------
__global__ __launch_bounds__(256, 2)
void gemm2_kernel(const unsigned short* __restrict__ h, const float* __restrict__ W2,
                  const float* __restrict__ b2, const int* __restrict__ perm,
                  const int* __restrict__ tile_e, float* __restrict__ out) {
  const int te = tile_e[blockIdx.x];
  if (te < 0) return;
  const float* W = W2 + (size_t)te * DMLP * DIM;
  const int n0 = blockIdx.y * BN;
  const int tid = threadIdx.x;

  __shared__ unsigned short As[BM][BK + 8];
  __shared__ unsigned short Bs[BN][BK + 8];

  const int arow = tid >> 1;
  const int acol = (tid & 1) * 16;
  const unsigned short* hrow = h + (size_t)(blockIdx.x * BM + arow) * DMLP + acol;

  const int bn  = tid & 127;
  const int bk0 = (tid >> 7) * 16;
  const float* wcol = W + n0 + bn;

  const int wid = tid >> 6, lane = tid & 63;
  const int wm = (wid >> 1) * 64, wn = (wid & 1) * 64;
  const int l15 = lane & 15, quad = lane >> 4;

  float4v acc[4][4];
#pragma unroll
  for (int i = 0; i < 4; i++)
#pragma unroll
    for (int j = 0; j < 4; j++) acc[i][j] = (float4v){0.f, 0.f, 0.f, 0.f};

  for (int k0 = 0; k0 < DMLP; k0 += BK) {
    // ---- stage A (h already bf16, straight 16B copies) ----
    short8 a0 = *(const short8*)(hrow + k0);
    short8 a1 = *(const short8*)(hrow + k0 + 8);
    *(short8*)&As[arow][acol]     = a0;
    *(short8*)&As[arow][acol + 8] = a1;

    // ---- stage B (W2 tile, transpose to [n][k], f32 -> bf16) ----
    float bv[16];
#pragma unroll
    for (int j = 0; j < 16; j++) bv[j] = wcol[(size_t)(k0 + bk0 + j) * DIM];
    short8 bp0, bp1;
#pragma unroll
    for (int q = 0; q < 8; q++) { bp0[q] = (short)f2bf(bv[q]); bp1[q] = (short)f2bf(bv[q + 8]); }
    *(short8*)&Bs[bn][bk0]     = bp0;
    *(short8*)&Bs[bn][bk0 + 8] = bp1;

    __syncthreads();

    short8 a[4], b[4];
#pragma unroll
    for (int i = 0; i < 4; i++) a[i] = *(short8*)&As[wm + i * 16 + l15][quad * 8];
#pragma unroll
    for (int j = 0; j < 4; j++) b[j] = *(short8*)&Bs[wn + j * 16 + l15][quad * 8];
#pragma unroll
    for (int i = 0; i < 4; i++)
#pragma unroll
      for (int j = 0; j < 4; j++)
        acc[i][j] = __builtin_amdgcn_mfma_f32_16x16x32_bf16(a[i], b[j], acc[i][j], 0, 0, 0);

    __syncthreads();
  }

  // ---- epilogue: bias, scatter f32 to assigned token ----
#pragma unroll
  for (int i = 0; i < 4; i++) {
#pragma unroll
    for (int j = 0; j < 4; j++) {
      const int col = n0 + wn + j * 16 + l15;
      const float bias = b2[te * DIM + col];
#pragma unroll
      for (int r = 0; r < 4; r++) {
        const int row  = wm + i * 16 + quad * 4 + r;
        const int slot = blockIdx.x * BM + row;
        const int t    = perm[slot];
        if (t >= 0) out[(size_t)t * DIM + col] = acc[i][j][r] + bias;
      }
    }
  }
}

// ---------------------------------------------------------------------------
extern "C" void kernel_launch(void* const* d_in, const int* in_sizes, int n_in,
                              void* d_out, int out_size, void* d_ws, size_t ws_size,
                              hipStream_t stream) {
  const float* x    = (const float*)d_in[0];
  const int*   eidx = (const int*)d_in[1];
  const float* W1   = (const float*)d_in[2];
  const float* b1   = (const float*)d_in[3];
  const float* W2   = (const float*)d_in[4];
  const float* b2   = (const float*)d_in[5];
  float* out = (float*)d_out;

  char* ws = (char*)d_ws;
  int* perm   = (int*)ws;                               // PADMAX ints
  int* tile_e = (int*)(ws + PADMAX * sizeof(int));      // NTILES ints
  unsigned short* h = (unsigned short*)(ws + 32768);    // PADMAX x DMLP bf16 (~40 MB)

  group_kernel<<<1, 256, 0, stream>>>(eidx, perm, tile_e);
  gemm1_kernel<<<dim3(NTILES, DMLP / BN), 256, 0, stream>>>(x, W1, b1, perm, tile_e, h);
  gemm2_kernel<<<dim3(NTILES, DIM / BN), 256, 0, stream>>>(h, W2, b2, perm, tile_e, out);
}

// Round 2
// 543.175 us; speedup vs baseline: 1.1997x; 1.1997x over previous
//
#include <hip/hip_runtime.h>
#include <hip/hip_bf16.h>
#include <math.h>

#define TOK   4096
#define DIM   1024
#define DMLP  4096
#define NE    8
#define BM    128
#define BN    128
#define BN2   64
#define BK    32
#define PADMAX (TOK + NE * BM)   // 5120 padded slots
#define NTILES (PADMAX / BM)     // 40 row-tiles

typedef __attribute__((ext_vector_type(8))) short  short8;
typedef __attribute__((ext_vector_type(4))) float  float4v;
typedef __attribute__((ext_vector_type(4))) unsigned short ushort4v;

static __device__ __forceinline__ unsigned short f2bf(float f) {
  unsigned u = __float_as_uint(f);
  u += 0x7fffu + ((u >> 16) & 1u);
  return (unsigned short)(u >> 16);
}

// ---------------------------------------------------------------------------
// Kernel 1: group tokens by expert (single block).
// ---------------------------------------------------------------------------
__global__ void group_kernel(const int* __restrict__ eidx,
                             int* __restrict__ perm,
                             int* __restrict__ tile_e) {
  __shared__ int cnt[NE], off[NE], len[NE], cur[NE];
  const int tid = threadIdx.x;
  if (tid < NE) cnt[tid] = 0;
  __syncthreads();
  for (int i = tid; i < TOK; i += 256) atomicAdd(&cnt[eidx[i]], 1);
  __syncthreads();
  if (tid == 0) {
    int o = 0;
    for (int e = 0; e < NE; e++) {
      off[e] = o;
      len[e] = ((cnt[e] + BM - 1) / BM) * BM;
      cur[e] = o;
      o += len[e];
    }
  }
  __syncthreads();
  for (int s = tid; s < PADMAX; s += 256) perm[s] = -1;
  __syncthreads();
  for (int i = tid; i < TOK; i += 256) {
    const int e = eidx[i];
    const int p = atomicAdd(&cur[e], 1);
    perm[p] = i;
  }
  __syncthreads();
  for (int t = tid; t < NTILES; t += 256) {
    const int row = t * BM;
    int te = -1;
    for (int e = 0; e < NE; e++)
      if (row >= off[e] && row < off[e] + len[e]) te = e;
    tile_e[t] = te;
  }
}

// ---------------------------------------------------------------------------
// Kernel 2: transpose + convert weights: W [E][K][N] f32 -> WT [E][N][K] bf16
// 64x64 tiles via LDS (row stride 66 -> conflict-free scattered writes).
// ---------------------------------------------------------------------------
__global__ __launch_bounds__(256)
void convtrans_kernel(const float* __restrict__ W, unsigned short* __restrict__ WT,
                      int K, int N) {
  __shared__ unsigned short T[64][66];
  const int e  = blockIdx.z;
  const int k0 = blockIdx.y * 64, n0 = blockIdx.x * 64;
  const float* Win = W + (size_t)e * K * N;
  unsigned short* Wout = WT + (size_t)e * K * N;
  const int tid = threadIdx.x;
  const int nl  = tid & 63;
  const int kb  = (tid >> 6) * 16;
#pragma unroll
  for (int r = 0; r < 16; r++) {
    const int kl = kb + r;
    T[nl][kl] = f2bf(Win[(size_t)(k0 + kl) * N + n0 + nl]);
  }
  __syncthreads();
  const int kc = (tid & 31) * 2;
  const int nb = tid >> 5;
#pragma unroll
  for (int r = 0; r < 8; r++) {
    const int nl2 = nb + r * 8;
    const unsigned v = *(const unsigned*)&T[nl2][kc];
    *(unsigned*)&Wout[(size_t)(n0 + nl2) * K + k0 + kc] = v;
  }
}

// ---------------------------------------------------------------------------
// Kernel 3: gather + convert x rows into permuted bf16 [PADMAX][DIM]
// ---------------------------------------------------------------------------
__global__ __launch_bounds__(256)
void xgather_kernel(const float* __restrict__ x, const int* __restrict__ perm,
                    unsigned short* __restrict__ xg) {
  const int slot = blockIdx.x;
  const int t    = perm[slot];
  const int tid  = threadIdx.x;
  ushort4v o = (ushort4v){0, 0, 0, 0};
  if (t >= 0) {
    const float4v v = *(const float4v*)(x + (size_t)t * DIM + tid * 4);
#pragma unroll
    for (int q = 0; q < 4; q++) o[q] = f2bf(v[q]);
  }
  *(ushort4v*)(xg + (size_t)slot * DIM + tid * 4) = o;
}

// ---------------------------------------------------------------------------
// Kernel 4: h = gelu(xg @ W1T^T + b1) -> bf16. 128x128 tile, BK=32.
// ---------------------------------------------------------------------------
__global__ __launch_bounds__(256, 2)
void gemm1_kernel(const unsigned short* __restrict__ xg,
                  const unsigned short* __restrict__ W1T,
                  const float* __restrict__ b1, const int* __restrict__ tile_e,
                  unsigned short* __restrict__ h) {
  const int te = tile_e[blockIdx.x];
  if (te < 0) return;
  const unsigned short* Bsrc = W1T + (size_t)te * DIM * DMLP; // [n][k]
  const int n0  = blockIdx.y * BN;
  const int tid = threadIdx.x;

  __shared__ unsigned short As[BM][BK + 8];
  __shared__ unsigned short Bs[BN][BK + 8];

  const int srow = tid >> 1;
  const int soff = (tid & 1) * 16;      // elements (bf16)
  const unsigned short* aptr = xg + (size_t)(blockIdx.x * BM + srow) * DIM + soff;
  const unsigned short* bptr = Bsrc + (size_t)(n0 + srow) * DIM + soff;

  const int wid = tid >> 6, lane = tid & 63;
  const int wm = (wid >> 1) * 64, wn = (wid & 1) * 64;
  const int l15 = lane & 15, quad = lane >> 4;

  float4v acc[4][4];
#pragma unroll
  for (int i = 0; i < 4; i++)
#pragma unroll
    for (int j = 0; j < 4; j++) acc[i][j] = (float4v){0.f, 0.f, 0.f, 0.f};

  for (int k0 = 0; k0 < DIM; k0 += BK) {
    const short8 a0 = *(const short8*)(aptr + k0);
    const short8 a1 = *(const short8*)(aptr + k0 + 8);
    const short8 b0 = *(const short8*)(bptr + k0);
    const short8 b1v = *(const short8*)(bptr + k0 + 8);
    *(short8*)&As[srow][soff]     = a0;
    *(short8*)&As[srow][soff + 8] = a1;
    *(short8*)&Bs[srow][soff]     = b0;
    *(short8*)&Bs[srow][soff + 8] = b1v;
    __syncthreads();

    short8 a[4], b[4];
#pragma unroll
    for (int i = 0; i < 4; i++) a[i] = *(short8*)&As[wm + i * 16 + l15][quad * 8];
#pragma unroll
    for (int j = 0; j < 4; j++) b[j] = *(short8*)&Bs[wn + j * 16 + l15][quad * 8];
#pragma unroll
    for (int i = 0; i < 4; i++)
#pragma unroll
      for (int j = 0; j < 4; j++)
        acc[i][j] = __builtin_amdgcn_mfma_f32_16x16x32_bf16(a[i], b[j], acc[i][j], 0, 0, 0);
    __syncthreads();
  }

#pragma unroll
  for (int i = 0; i < 4; i++) {
#pragma unroll
    for (int j = 0; j < 4; j++) {
      const int col = n0 + wn + j * 16 + l15;
      const float bias = b1[te * DMLP + col];
#pragma unroll
      for (int r = 0; r < 4; r++) {
        const int row = wm + i * 16 + quad * 4 + r;
        float v = acc[i][j][r] + bias;
        v = 0.5f * v * (1.0f + erff(v * 0.7071067811865475f));
        h[(size_t)(blockIdx.x * BM + row) * DMLP + col] = f2bf(v);
      }
    }
  }
}

// ---------------------------------------------------------------------------
// Kernel 5: out[tok] = h @ W2T^T + b2, scatter. 128x64 tile, BK=32.
// ---------------------------------------------------------------------------
__global__ __launch_bounds__(256, 2)
void gemm2_kernel(const unsigned short* __restrict__ h,
                  const unsigned short* __restrict__ W2T,
                  const float* __restrict__ b2, const int* __restrict__ perm,
                  const int* __restrict__ tile_e, float* __restrict__ out) {
  const int te = tile_e[blockIdx.x];
  if (te < 0) return;
  const unsigned short* Bsrc = W2T + (size_t)te * DMLP * DIM; // [n=DIM][k=DMLP]
  const int n0  = blockIdx.y * BN2;
  const int tid = threadIdx.x;

  __shared__ unsigned short As[BM][BK + 8];
  __shared__ unsigned short Bs[BN2][BK + 8];

  const int arow = tid >> 1;
  const int aoff = (tid & 1) * 16;
  const unsigned short* aptr = h + (size_t)(blockIdx.x * BM + arow) * DMLP + aoff;

  const int brow = tid >> 2;
  const int boff = (tid & 3) * 8;
  const unsigned short* bptr = Bsrc + (size_t)(n0 + brow) * DMLP + boff;

  const int wid = tid >> 6, lane = tid & 63;
  const int wm = (wid >> 1) * 64, wn = (wid & 1) * 32;
  const int l15 = lane & 15, quad = lane >> 4;

  float4v acc[4][2];
#pragma unroll
  for (int i = 0; i < 4; i++)
#pragma unroll
    for (int j = 0; j < 2; j++) acc[i][j] = (float4v){0.f, 0.f, 0.f, 0.f};

  for (int k0 = 0; k0 < DMLP; k0 += BK) {
    const short8 a0 = *(const short8*)(aptr + k0);
    const short8 a1 = *(const short8*)(aptr + k0 + 8);
    const short8 b0 = *(const short8*)(bptr + k0);
    *(short8*)&As[arow][aoff]     = a0;
    *(short8*)&As[arow][aoff + 8] = a1;
    *(short8*)&Bs[brow][boff]     = b0;
    __syncthreads();

    short8 a[4], b[2];
#pragma unroll
    for (int i = 0; i < 4; i++) a[i] = *(short8*)&As[wm + i * 16 + l15][quad * 8];
#pragma unroll
    for (int j = 0; j < 2; j++) b[j] = *(short8*)&Bs[wn + j * 16 + l15][quad * 8];
#pragma unroll
    for (int i = 0; i < 4; i++)
#pragma unroll
      for (int j = 0; j < 2; j++)
        acc[i][j] = __builtin_amdgcn_mfma_f32_16x16x32_bf16(a[i], b[j], acc[i][j], 0, 0, 0);
    __syncthreads();
  }

#pragma unroll
  for (int i = 0; i < 4; i++) {
#pragma unroll
    for (int j = 0; j < 2; j++) {
      const int col = n0 + wn + j * 16 + l15;
      const float bias = b2[te * DIM + col];
#pragma unroll
      for (int r = 0; r < 4; r++) {
        const int row  = wm + i * 16 + quad * 4 + r;
        const int slot = blockIdx.x * BM + row;
        const int t    = perm[slot];
        if (t >= 0) out[(size_t)t * DIM + col] = acc[i][j][r] + bias;
      }
    }
  }
}

// ---------------------------------------------------------------------------
extern "C" void kernel_launch(void* const* d_in, const int* in_sizes, int n_in,
                              void* d_out, int out_size, void* d_ws, size_t ws_size,
                              hipStream_t stream) {
  const float* x    = (const float*)d_in[0];
  const int*   eidx = (const int*)d_in[1];
  const float* W1   = (const float*)d_in[2];
  const float* b1   = (const float*)d_in[3];
  const float* W2   = (const float*)d_in[4];
  const float* b2   = (const float*)d_in[5];
  float* out = (float*)d_out;

  char* ws = (char*)d_ws;
  int* perm   = (int*)ws;                              // PADMAX ints
  int* tile_e = (int*)(ws + PADMAX * sizeof(int));     // NTILES ints
  unsigned short* xg  = (unsigned short*)(ws + 32768);                      // 10 MB
  unsigned short* h   = (unsigned short*)(ws + 32768 + 10485760);           // 40 MB
  unsigned short* W1T = (unsigned short*)(ws + 32768 + 10485760 + 41943040);// 64 MB
  unsigned short* W2T = (unsigned short*)((char*)W1T + 67108864);           // 64 MB

  group_kernel<<<1, 256, 0, stream>>>(eidx, perm, tile_e);
  convtrans_kernel<<<dim3(DMLP / 64, DIM / 64, NE), 256, 0, stream>>>(W1, W1T, DIM, DMLP);
  convtrans_kernel<<<dim3(DIM / 64, DMLP / 64, NE), 256, 0, stream>>>(W2, W2T, DMLP, DIM);
  xgather_kernel<<<PADMAX, 256, 0, stream>>>(x, perm, xg);
  gemm1_kernel<<<dim3(NTILES, DMLP / BN), 256, 0, stream>>>(xg, W1T, b1, tile_e, h);
  gemm2_kernel<<<dim3(NTILES, DIM / BN2), 256, 0, stream>>>(h, W2T, b2, perm, tile_e, out);
}

// Round 3
// 494.320 us; speedup vs baseline: 1.3183x; 1.0988x over previous
//
#include <hip/hip_runtime.h>
#include <hip/hip_bf16.h>
#include <math.h>

#define TOK   4096
#define DIM   1024
#define DMLP  4096
#define NE    8
#define BM    128
#define BN    128
#define BN2   64
#define BK    64
#define PADMAX (TOK + NE * BM)   // 5120 padded slots
#define NTILES (PADMAX / BM)     // 40 row-tiles

typedef __attribute__((ext_vector_type(8))) short  short8;
typedef __attribute__((ext_vector_type(4))) float  float4v;
typedef __attribute__((ext_vector_type(4))) unsigned short ushort4v;

// async global->LDS, 16 B per lane; LDS dest is wave-uniform base + lane*16
#define ASYNC16(gp, lp) __builtin_amdgcn_global_load_lds( \
    (const __attribute__((address_space(1))) unsigned int*)(gp), \
    (__attribute__((address_space(3))) unsigned int*)(lp), 16, 0, 0)

// swizzled granule offset (shorts) for row R, k-chunk C (granule = 8 bf16 = 16 B)
#define FRAG_OFF(R, C) (((((R) << 3) + ((C) ^ ((R) & 7)))) << 3)

static __device__ __forceinline__ unsigned short f2bf(float f) {
  unsigned u = __float_as_uint(f);
  u += 0x7fffu + ((u >> 16) & 1u);
  return (unsigned short)(u >> 16);
}

// ---------------------------------------------------------------------------
// Kernel 1: group tokens by expert (single block).
// ---------------------------------------------------------------------------
__global__ void group_kernel(const int* __restrict__ eidx,
                             int* __restrict__ perm,
                             int* __restrict__ tile_e) {
  __shared__ int cnt[NE], off[NE], len[NE], cur[NE];
  const int tid = threadIdx.x;
  if (tid < NE) cnt[tid] = 0;
  __syncthreads();
  for (int i = tid; i < TOK; i += 256) atomicAdd(&cnt[eidx[i]], 1);
  __syncthreads();
  if (tid == 0) {
    int o = 0;
    for (int e = 0; e < NE; e++) {
      off[e] = o;
      len[e] = ((cnt[e] + BM - 1) / BM) * BM;
      cur[e] = o;
      o += len[e];
    }
  }
  __syncthreads();
  for (int s = tid; s < PADMAX; s += 256) perm[s] = -1;
  __syncthreads();
  for (int i = tid; i < TOK; i += 256) {
    const int e = eidx[i];
    const int p = atomicAdd(&cur[e], 1);
    perm[p] = i;
  }
  __syncthreads();
  for (int t = tid; t < NTILES; t += 256) {
    const int row = t * BM;
    int te = -1;
    for (int e = 0; e < NE; e++)
      if (row >= off[e] && row < off[e] + len[e]) te = e;
    tile_e[t] = te;
  }
}

// ---------------------------------------------------------------------------
// Kernel 2: transpose + convert weights: W [E][K][N] f32 -> WT [E][N][K] bf16
// ---------------------------------------------------------------------------
__global__ __launch_bounds__(256)
void convtrans_kernel(const float* __restrict__ W, unsigned short* __restrict__ WT,
                      int K, int N) {
  __shared__ unsigned short T[64][66];
  const int e  = blockIdx.z;
  const int k0 = blockIdx.y * 64, n0 = blockIdx.x * 64;
  const float* Win = W + (size_t)e * K * N;
  unsigned short* Wout = WT + (size_t)e * K * N;
  const int tid = threadIdx.x;
  const int nl  = tid & 63;
  const int kb  = (tid >> 6) * 16;
#pragma unroll
  for (int r = 0; r < 16; r++) {
    const int kl = kb + r;
    T[nl][kl] = f2bf(Win[(size_t)(k0 + kl) * N + n0 + nl]);
  }
  __syncthreads();
  const int kc = (tid & 31) * 2;
  const int nb = tid >> 5;
#pragma unroll
  for (int r = 0; r < 8; r++) {
    const int nl2 = nb + r * 8;
    const unsigned v = *(const unsigned*)&T[nl2][kc];
    *(unsigned*)&Wout[(size_t)(n0 + nl2) * K + k0 + kc] = v;
  }
}

// ---------------------------------------------------------------------------
// Kernel 3: gather + convert x rows into permuted bf16 [PADMAX][DIM]
// ---------------------------------------------------------------------------
__global__ __launch_bounds__(256)
void xgather_kernel(const float* __restrict__ x, const int* __restrict__ perm,
                    unsigned short* __restrict__ xg) {
  const int slot = blockIdx.x;
  const int t    = perm[slot];
  const int tid  = threadIdx.x;
  ushort4v o = (ushort4v){0, 0, 0, 0};
  if (t >= 0) {
    const float4v v = *(const float4v*)(x + (size_t)t * DIM + tid * 4);
#pragma unroll
    for (int q = 0; q < 4; q++) o[q] = f2bf(v[q]);
  }
  *(ushort4v*)(xg + (size_t)slot * DIM + tid * 4) = o;
}

// ---------------------------------------------------------------------------
// Kernel 4: h = gelu(xg @ W1T^T + b1) -> bf16. 128x128 tile, BK=64,
// async global_load_lds staging, XOR-swizzled LDS.
// ---------------------------------------------------------------------------
__global__ __launch_bounds__(256)
void gemm1_kernel(const unsigned short* __restrict__ xg,
                  const unsigned short* __restrict__ W1T,
                  const float* __restrict__ b1, const int* __restrict__ tile_e,
                  unsigned short* __restrict__ h) {
  const int te = tile_e[blockIdx.x];
  if (te < 0) return;
  const unsigned short* Asrc = xg + (size_t)blockIdx.x * BM * DIM;
  const unsigned short* Bsrc = W1T + (size_t)te * DIM * DMLP + (size_t)(blockIdx.y * BN) * DIM;
  const int tid = threadIdx.x;

  __shared__ __align__(16) unsigned short As[BM * BK];   // 16 KB
  __shared__ __align__(16) unsigned short Bs[BN * BK];   // 16 KB

  // staging maps: issue t, this thread -> granule p = t*256+tid
  const unsigned short* ag[4];
  const unsigned short* bg[4];
  int lo[4];
#pragma unroll
  for (int t = 0; t < 4; t++) {
    const int p = t * 256 + tid;
    const int r = p >> 3;
    const int c = (p & 7) ^ (r & 7);
    ag[t] = Asrc + (size_t)r * DIM + c * 8;
    bg[t] = Bsrc + (size_t)r * DIM + c * 8;
    lo[t] = p * 8;
  }

  const int wid = tid >> 6, lane = tid & 63;
  const int wm = (wid >> 1) * 64, wn = (wid & 1) * 64;
  const int l15 = lane & 15, quad = lane >> 4;

  float4v acc[4][4];
#pragma unroll
  for (int i = 0; i < 4; i++)
#pragma unroll
    for (int j = 0; j < 4; j++) acc[i][j] = (float4v){0.f, 0.f, 0.f, 0.f};

  for (int k0 = 0; k0 < DIM; k0 += BK) {
#pragma unroll
    for (int t = 0; t < 4; t++) ASYNC16(ag[t] + k0, &As[lo[t]]);
#pragma unroll
    for (int t = 0; t < 4; t++) ASYNC16(bg[t] + k0, &Bs[lo[t]]);
    __syncthreads();

#pragma unroll
    for (int hh = 0; hh < 2; hh++) {
      short8 a[4], b[4];
      const int C = hh * 4 + quad;
#pragma unroll
      for (int i = 0; i < 4; i++) a[i] = *(const short8*)&As[FRAG_OFF(wm + i * 16 + l15, C)];
#pragma unroll
      for (int j = 0; j < 4; j++) b[j] = *(const short8*)&Bs[FRAG_OFF(wn + j * 16 + l15, C)];
#pragma unroll
      for (int i = 0; i < 4; i++)
#pragma unroll
        for (int j = 0; j < 4; j++)
          acc[i][j] = __builtin_amdgcn_mfma_f32_16x16x32_bf16(a[i], b[j], acc[i][j], 0, 0, 0);
    }
    __syncthreads();
  }

#pragma unroll
  for (int i = 0; i < 4; i++) {
#pragma unroll
    for (int j = 0; j < 4; j++) {
      const int col = blockIdx.y * BN + wn + j * 16 + l15;
      const float bias = b1[te * DMLP + col];
#pragma unroll
      for (int r = 0; r < 4; r++) {
        const int row = wm + i * 16 + quad * 4 + r;
        float v = acc[i][j][r] + bias;
        v = 0.5f * v * (1.0f + erff(v * 0.7071067811865475f));
        h[(size_t)(blockIdx.x * BM + row) * DMLP + col] = f2bf(v);
      }
    }
  }
}

// ---------------------------------------------------------------------------
// Kernel 5: out[tok] = h @ W2T^T + b2, scatter. 128x64 tile, BK=64, async.
// ---------------------------------------------------------------------------
__global__ __launch_bounds__(256)
void gemm2_kernel(const unsigned short* __restrict__ h,
                  const unsigned short* __restrict__ W2T,
                  const float* __restrict__ b2, const int* __restrict__ perm,
                  const int* __restrict__ tile_e, float* __restrict__ out) {
  const int te = tile_e[blockIdx.x];
  if (te < 0) return;
  const unsigned short* Asrc = h + (size_t)blockIdx.x * BM * DMLP;
  const unsigned short* Bsrc = W2T + (size_t)te * DMLP * DIM + (size_t)(blockIdx.y * BN2) * DMLP;
  const int tid = threadIdx.x;

  __shared__ __align__(16) unsigned short As[BM * BK];    // 16 KB
  __shared__ __align__(16) unsigned short Bs[BN2 * BK];   // 8 KB

  const unsigned short* ag[4];
  const unsigned short* bg[2];
  int alo[4], blo[2];
#pragma unroll
  for (int t = 0; t < 4; t++) {
    const int p = t * 256 + tid;
    const int r = p >> 3;
    const int c = (p & 7) ^ (r & 7);
    ag[t] = Asrc + (size_t)r * DMLP + c * 8;
    alo[t] = p * 8;
  }
#pragma unroll
  for (int t = 0; t < 2; t++) {
    const int p = t * 256 + tid;
    const int r = p >> 3;
    const int c = (p & 7) ^ (r & 7);
    bg[t] = Bsrc + (size_t)r * DMLP + c * 8;
    blo[t] = p * 8;
  }

  const int wid = tid >> 6, lane = tid & 63;
  const int wm = (wid >> 1) * 64, wn = (wid & 1) * 32;
  const int l15 = lane & 15, quad = lane >> 4;

  float4v acc[4][2];
#pragma unroll
  for (int i = 0; i < 4; i++)
#pragma unroll
    for (int j = 0; j < 2; j++) acc[i][j] = (float4v){0.f, 0.f, 0.f, 0.f};

  for (int k0 = 0; k0 < DMLP; k0 += BK) {
#pragma unroll
    for (int t = 0; t < 4; t++) ASYNC16(ag[t] + k0, &As[alo[t]]);
#pragma unroll
    for (int t = 0; t < 2; t++) ASYNC16(bg[t] + k0, &Bs[blo[t]]);
    __syncthreads();

#pragma unroll
    for (int hh = 0; hh < 2; hh++) {
      short8 a[4], b[2];
      const int C = hh * 4 + quad;
#pragma unroll
      for (int i = 0; i < 4; i++) a[i] = *(const short8*)&As[FRAG_OFF(wm + i * 16 + l15, C)];
#pragma unroll
      for (int j = 0; j < 2; j++) b[j] = *(const short8*)&Bs[FRAG_OFF(wn + j * 16 + l15, C)];
#pragma unroll
      for (int i = 0; i < 4; i++)
#pragma unroll
        for (int j = 0; j < 2; j++)
          acc[i][j] = __builtin_amdgcn_mfma_f32_16x16x32_bf16(a[i], b[j], acc[i][j], 0, 0, 0);
    }
    __syncthreads();
  }

#pragma unroll
  for (int i = 0; i < 4; i++) {
#pragma unroll
    for (int j = 0; j < 2; j++) {
      const int col = blockIdx.y * BN2 + wn + j * 16 + l15;
      const float bias = b2[te * DIM + col];
#pragma unroll
      for (int r = 0; r < 4; r++) {
        const int row  = wm + i * 16 + quad * 4 + r;
        const int slot = blockIdx.x * BM + row;
        const int t    = perm[slot];
        if (t >= 0) out[(size_t)t * DIM + col] = acc[i][j][r] + bias;
      }
    }
  }
}

// ---------------------------------------------------------------------------
extern "C" void kernel_launch(void* const* d_in, const int* in_sizes, int n_in,
                              void* d_out, int out_size, void* d_ws, size_t ws_size,
                              hipStream_t stream) {
  const float* x    = (const float*)d_in[0];
  const int*   eidx = (const int*)d_in[1];
  const float* W1   = (const float*)d_in[2];
  const float* b1   = (const float*)d_in[3];
  const float* W2   = (const float*)d_in[4];
  const float* b2   = (const float*)d_in[5];
  float* out = (float*)d_out;

  char* ws = (char*)d_ws;
  int* perm   = (int*)ws;                              // PADMAX ints
  int* tile_e = (int*)(ws + PADMAX * sizeof(int));     // NTILES ints
  unsigned short* xg  = (unsigned short*)(ws + 32768);                      // 10 MB
  unsigned short* h   = (unsigned short*)(ws + 32768 + 10485760);           // 40 MB
  unsigned short* W1T = (unsigned short*)(ws + 32768 + 10485760 + 41943040);// 64 MB
  unsigned short* W2T = (unsigned short*)((char*)W1T + 67108864);           // 64 MB

  group_kernel<<<1, 256, 0, stream>>>(eidx, perm, tile_e);
  convtrans_kernel<<<dim3(DMLP / 64, DIM / 64, NE), 256, 0, stream>>>(W1, W1T, DIM, DMLP);
  convtrans_kernel<<<dim3(DIM / 64, DMLP / 64, NE), 256, 0, stream>>>(W2, W2T, DMLP, DIM);
  xgather_kernel<<<PADMAX, 256, 0, stream>>>(x, perm, xg);
  gemm1_kernel<<<dim3(NTILES, DMLP / BN), 256, 0, stream>>>(xg, W1T, b1, tile_e, h);
  gemm2_kernel<<<dim3(NTILES, DIM / BN2), 256, 0, stream>>>(h, W2T, b2, perm, tile_e, out);
}